// Round 8
// baseline (485.614 us; speedup 1.0000x reference)
//
#include <hip/hip_runtime.h>
#include <math.h>

#define NN   50000
#define EE   800000
#define EF   850000   // EE + NN self loops
#define HH   128
#define FE   16
#define LATD 64
#define MAXNN 200

#define ADJ_TOT   10000000   // NN*MAXNN
#define NODES_TOT 6400000    // NN*HH
#define OUT_TOT   16400000   // ADJ_TOT + NODES_TOT
#define MU_OFF    16400000
#define LV_OFF    16400064

__device__ __forceinline__ unsigned short f2bf(float f){
  unsigned int u = __float_as_uint(f);
  unsigned int r = (u + 0x7FFFu + ((u>>16)&1u)) >> 16;   // RNE
  return (unsigned short)r;
}
__device__ __forceinline__ float bf2f(unsigned short h){
  return __uint_as_float(((unsigned int)h)<<16);
}

// ---------------- init ----------------
__global__ void kinit(int* ideg, float* hgsum){
  int i = blockIdx.x*blockDim.x + threadIdx.x;
  if(i < NN) ideg[i]=0;
  if(i < HH) hgsum[i]=0.f;
}

// wa[f] = sum_j We[f][j]*att_e[j]   (fold edge-MLP into 16-vector)
__global__ void kwa(const float* We1, const float* ae1, const float* We2, const float* ae2,
                    float* wa1, float* wa2){
  int t = threadIdx.x;
  if(t < FE){
    float s1=0.f, s2=0.f;
    for(int j=0;j<HH;j++){ s1 += We1[t*HH+j]*ae1[j]; s2 += We2[t*HH+j]*ae2[j]; }
    wa1[t]=s1; wa2[t]=s2;
  }
}

// degree count + within-row rank (atomic return) — removes the atomic from kscatter
__global__ void kdeg(const int* __restrict__ ei, int* ideg, int* __restrict__ erank){
  int e = blockIdx.x*blockDim.x + threadIdx.x;
  if(e<EE) erank[e] = atomicAdd(&ideg[ei[EE+e]], 1);
}

// ---------------- exclusive scan of rowlen = ideg+1 ----------------
__global__ void kscan1(const int* __restrict__ ideg, int* rowstart, int* blocksum){
  __shared__ int sd[1024];
  int t=threadIdx.x; int i=blockIdx.x*1024+t;
  int v = (i<NN)? (ideg[i]+1) : 0;
  sd[t]=v; __syncthreads();
  for(int off=1; off<1024; off<<=1){
    int x = (t>=off)? sd[t-off] : 0;
    __syncthreads();
    sd[t] += x;
    __syncthreads();
  }
  if(i<NN) rowstart[i] = sd[t]-v;
  if(t==1023) blocksum[blockIdx.x]=sd[1023];
}
__global__ void kscan2(const int* blocksum, int* blockoff, int nb){
  if(threadIdx.x==0){
    int run=0;
    for(int b=0;b<nb;b++){ blockoff[b]=run; run+=blocksum[b]; }
    blockoff[nb]=run;
  }
}
__global__ void kscan3(int* rowstart, const int* __restrict__ blockoff, int nb){
  int i=blockIdx.x*blockDim.x+threadIdx.x;
  if(i<NN) rowstart[i]+=blockoff[i>>10];
  if(i==0) rowstart[NN]=blockoff[nb];
}

// ---------------- CSR scatter: one packed 16B entry per edge, NO atomic ----------------
// entry = {src (int bits), et1, et2, pad}
__global__ void kscatter(const int* __restrict__ ei, const float* __restrict__ ea,
                         const float* __restrict__ wa1, const float* __restrict__ wa2,
                         const int* __restrict__ rowstart, const int* __restrict__ erank,
                         float4* __restrict__ csr){
  int e=blockIdx.x*blockDim.x+threadIdx.x;
  if(e>=EE) return;
  int s=ei[e], d=ei[EE+e];
  const float4* ea4 = (const float4*)(ea + (size_t)e*FE);
  float4 v0=ea4[0], v1=ea4[1], v2=ea4[2], v3=ea4[3];
  float va[16]={v0.x,v0.y,v0.z,v0.w, v1.x,v1.y,v1.z,v1.w,
                v2.x,v2.y,v2.z,v2.w, v3.x,v3.y,v3.z,v3.w};
  float d1=0.f,d2=0.f;
  #pragma unroll
  for(int f=0;f<FE;f++){ d1+=va[f]*wa1[f]; d2+=va[f]*wa2[f]; }
  int pos = rowstart[d] + erank[e];
  csr[pos] = make_float4(__int_as_float(s), d1, d2, 0.f);
}

// self-loop entry: et = mean of row's et values
// 16-lane group per node: coalesced reads + shfl_xor(16) reduction
__global__ __launch_bounds__(256) void kself(const int* __restrict__ rowstart,
                      const int* __restrict__ ideg,
                      float4* __restrict__ csr){
  int tid = threadIdx.x;
  int l16 = tid & 15;
  int grp = tid >> 4;               // 16 groups per block
  int i = blockIdx.x*16 + grp;
  if(i>=NN) return;
  int base = rowstart[i]; int deg = ideg[i];
  float s1=0.f, s2=0.f;
  for(int k=l16;k<deg;k+=16){ float4 en=csr[base+k]; s1+=en.y; s2+=en.z; }
  #pragma unroll
  for(int m=8;m>=1;m>>=1){ s1+=__shfl_xor(s1,m,16); s2+=__shfl_xor(s2,m,16); }
  if(l16==0){
    float dg = (float)deg; if(dg<1.f) dg=1.f;
    csr[base+deg] = make_float4(__int_as_float(i), s1/dg, s2/dg, 0.f);
  }
}

// ---------------- tiled fp32 GEMM: Gbf = bf16(h @ W), plus asrc/adst row dots ----------------
// tile: 64 rows x 128 cols; 256 threads; thread micro-tile 4x8. LDS 32 KB -> 3+ blocks/CU.
__global__ __launch_bounds__(256) void kgemm2(const float* __restrict__ hin,
    const float* __restrict__ W,
    const float* __restrict__ atts, const float* __restrict__ attd,
    unsigned short* __restrict__ Gbf, float* __restrict__ asrc, float* __restrict__ adst){
  __shared__ float hs[64*HH];     // 32 KB, swizzled
  int t = threadIdx.x;
  int row0 = blockIdx.x * 64;
  // stage 64 rows: 2048 float4, 8 iters of 256
  #pragma unroll
  for(int it=0; it<8; ++it){
    int f = it*256 + t;          // float4 index 0..2047
    int r = f >> 5;              // 32 float4-chunks per row
    int c4 = f & 31;
    int grow = row0 + r;
    float4 v = make_float4(0.f,0.f,0.f,0.f);
    if(grow < NN) v = *(const float4*)(hin + (size_t)grow*HH + c4*4);
    int sc4 = c4 ^ ((r>>3)&3);
    *(float4*)(hs + r*HH + sc4*4) = v;
  }
  __syncthreads();

  int tcg = t & 15;              // col group: cols c0..c0+7
  int trg = t >> 4;              // row group 0..15: rows r0..r0+3
  int c0  = tcg*8;
  int r0  = trg*4;
  int sw  = (trg>>1)&3;          // read-side swizzle ( (r>>3)&3 for rows r0..r0+3 )

  float s_att[8], d_att[8];
  #pragma unroll
  for(int c=0;c<8;c++){ s_att[c]=atts[c0+c]; d_att[c]=attd[c0+c]; }

  float acc[4][8];
  #pragma unroll
  for(int r=0;r<4;r++)
    #pragma unroll
    for(int c=0;c<8;c++) acc[r][c]=0.f;

  for(int k=0;k<HH;k+=4){
    int k4 = k>>2;
    float4 hv[4];
    #pragma unroll
    for(int r=0;r<4;r++)
      hv[r] = *(const float4*)(hs + (r0+r)*HH + ((k4 ^ sw)<<2));
    #pragma unroll
    for(int kk=0;kk<4;kk++){
      float4 w0 = *(const float4*)(W + (size_t)(k+kk)*HH + c0);
      float4 w1 = *(const float4*)(W + (size_t)(k+kk)*HH + c0 + 4);
      float wz[8] = {w0.x,w0.y,w0.z,w0.w,w1.x,w1.y,w1.z,w1.w};
      #pragma unroll
      for(int r=0;r<4;r++){
        float hval = (kk==0)?hv[r].x : (kk==1)?hv[r].y : (kk==2)?hv[r].z : hv[r].w;
        #pragma unroll
        for(int c=0;c<8;c++) acc[r][c] += hval * wz[c];
      }
    }
  }

  #pragma unroll
  for(int r=0;r<4;r++){
    int grow = row0 + r0 + r;
    float ps=0.f, pd=0.f;
    #pragma unroll
    for(int c=0;c<8;c++){ ps += acc[r][c]*s_att[c]; pd += acc[r][c]*d_att[c]; }
    #pragma unroll
    for(int m=8;m>=1;m>>=1){ ps += __shfl_xor(ps,m,16); pd += __shfl_xor(pd,m,16); }
    if(grow < NN){
      uint4 o;
      o.x = (unsigned)f2bf(acc[r][0]) | ((unsigned)f2bf(acc[r][1])<<16);
      o.y = (unsigned)f2bf(acc[r][2]) | ((unsigned)f2bf(acc[r][3])<<16);
      o.z = (unsigned)f2bf(acc[r][4]) | ((unsigned)f2bf(acc[r][5])<<16);
      o.w = (unsigned)f2bf(acc[r][6]) | ((unsigned)f2bf(acc[r][7])<<16);
      *(uint4*)(Gbf + (size_t)grow*HH + c0) = o;   // 16B aligned (c0 mult of 8)
      if(tcg==0){ asrc[grow]=ps; adst[grow]=pd; }
    }
  }
}

// ---------------- GAT softmax-aggregate: ONE WAVE per dst node, no LDS/barriers ----
// 4-deep software-pipelined gather: 4 independent row loads in flight.
__global__ __launch_bounds__(256) void kgat(const unsigned short* __restrict__ A,
    const float* __restrict__ asrc, const float* __restrict__ adst,
    const int* __restrict__ rowstart, const float4* __restrict__ csr,
    int etsel, const float* __restrict__ bias,
    float* __restrict__ alphabuf, int* __restrict__ srcbuf,
    float* __restrict__ Bout){
  int lane = threadIdx.x & 63;
  int wid  = threadIdx.x >> 6;
  int i = blockIdx.x*4 + wid;
  if(i >= NN) return;
  int base = rowstart[i]; int len = rowstart[i+1]-base;
  float adi = adst[i];
  float acc0=0.f, acc1=0.f;
  float den;
  if(__builtin_expect(len <= 64, 1)){
    float a = -1e30f; int s=0;
    if(lane < len){
      float4 en = csr[base+lane];
      s = __float_as_int(en.x);
      float et = etsel ? en.z : en.y;
      a = asrc[s] + adi + et;
      a = a>0.f ? a : 0.2f*a;            // leaky_relu 0.2
    }
    float m = a;
    #pragma unroll
    for(int mk=32;mk>=1;mk>>=1) m = fmaxf(m, __shfl_xor(m, mk));
    float ex = (lane<len) ? __expf(a-m) : 0.f;
    float sm = ex;
    #pragma unroll
    for(int mk=32;mk>=1;mk>>=1) sm += __shfl_xor(sm, mk);
    den = sm;
    const unsigned short* Ap = A + lane*2;
    int k=0;
    for(; k+4<=len; k+=4){
      float wk0=__shfl(ex,k+0); int sk0=__shfl(s,k+0);
      float wk1=__shfl(ex,k+1); int sk1=__shfl(s,k+1);
      float wk2=__shfl(ex,k+2); int sk2=__shfl(s,k+2);
      float wk3=__shfl(ex,k+3); int sk3=__shfl(s,k+3);
      unsigned p0 = *(const unsigned*)(Ap + (size_t)sk0*HH);
      unsigned p1 = *(const unsigned*)(Ap + (size_t)sk1*HH);
      unsigned p2 = *(const unsigned*)(Ap + (size_t)sk2*HH);
      unsigned p3 = *(const unsigned*)(Ap + (size_t)sk3*HH);
      acc0 += wk0 * __uint_as_float(p0<<16);
      acc1 += wk0 * __uint_as_float(p0 & 0xFFFF0000u);
      acc0 += wk1 * __uint_as_float(p1<<16);
      acc1 += wk1 * __uint_as_float(p1 & 0xFFFF0000u);
      acc0 += wk2 * __uint_as_float(p2<<16);
      acc1 += wk2 * __uint_as_float(p2 & 0xFFFF0000u);
      acc0 += wk3 * __uint_as_float(p3<<16);
      acc1 += wk3 * __uint_as_float(p3 & 0xFFFF0000u);
    }
    for(; k<len; k++){
      float wk = __shfl(ex, k);
      int   sk = __shfl(s, k);
      unsigned pr = *(const unsigned*)(Ap + (size_t)sk*HH);
      acc0 += wk * __uint_as_float(pr<<16);
      acc1 += wk * __uint_as_float(pr & 0xFFFF0000u);
    }
  } else {
    // rare fallback: strided two-pass with global spill
    float lm = -1e30f;
    for(int k=lane;k<len;k+=64){
      float4 en = csr[base+k];
      int s = __float_as_int(en.x);
      float et = etsel ? en.z : en.y;
      float a = asrc[s] + adi + et;
      a = a>0.f ? a : 0.2f*a;
      alphabuf[base+k]=a; srcbuf[base+k]=s;
      lm = fmaxf(lm,a);
    }
    #pragma unroll
    for(int mk=32;mk>=1;mk>>=1) lm = fmaxf(lm, __shfl_xor(lm, mk));
    float ls=0.f;
    for(int k=lane;k<len;k+=64){
      float ex = __expf(alphabuf[base+k]-lm);
      alphabuf[base+k]=ex; ls+=ex;
    }
    #pragma unroll
    for(int mk=32;mk>=1;mk>>=1) ls += __shfl_xor(ls, mk);
    den = ls;
    for(int c=0;c<len;c+=64){
      int kk = c+lane;
      float w = (kk<len)? alphabuf[base+kk] : 0.f;
      int   s = (kk<len)? srcbuf[base+kk] : 0;
      int lim = min(64, len-c);
      for(int j=0;j<lim;j++){
        float wk = __shfl(w, j);
        int   sk = __shfl(s, j);
        unsigned pr = *(const unsigned*)(A + (size_t)sk*HH + lane*2);
        acc0 += wk * __uint_as_float(pr<<16);
        acc1 += wk * __uint_as_float(pr & 0xFFFF0000u);
      }
    }
  }
  float inv = 1.f/den;
  float2 bb = *(const float2*)(bias + lane*2);
  float2 o;
  o.x = fmaxf(acc0*inv + bb.x, 0.f);
  o.y = fmaxf(acc1*inv + bb.y, 0.f);
  *(float2*)(Bout + (size_t)i*HH + lane*2) = o;
}

// ---------------- column mean: grid-strided, 512 blocks ----------------
__global__ __launch_bounds__(256) void khg(const float* __restrict__ B, float* hgsum){
  int f = threadIdx.x & 127;      // column
  int half = threadIdx.x >> 7;    // 0/1
  float s=0.f;
  for(int i = blockIdx.x*2+half; i < NN; i += gridDim.x*2)
    s += B[(size_t)i*HH + f];
  __shared__ float sd[256];
  sd[threadIdx.x]=s; __syncthreads();
  if(half==0) atomicAdd(&hgsum[f], sd[threadIdx.x]+sd[threadIdx.x+128]);
}

// ---------------- tiny decoder, single block ----------------
__global__ __launch_bounds__(256) void kdec(const float* __restrict__ hgsum, const float* __restrict__ eps,
   const float* muW,const float* mub,const float* lvW,const float* lvb,
   const float* decW,const float* decb,
   const float* aW1,const float* ab1,const float* aW2,const float* ab2,
   const float* nW1,const float* nb1,const float* nW2,const float* nb2,
   float* out, float* rowadj, float* rownodes){
  __shared__ float hg[HH], z[LATD], hd[HH], t1[HH], t2[HH];
  int t=threadIdx.x;
  if(t<HH) hg[t]=hgsum[t]*(1.0f/NN);
  __syncthreads();
  if(t<LATD){
    float mu=mub[t], lv=lvb[t];
    for(int k=0;k<HH;k++){ mu += hg[k]*muW[k*LATD+t]; lv += hg[k]*lvW[k*LATD+t]; }
    out[MU_OFF+t]=mu; out[LV_OFF+t]=lv;
    z[t]=mu + eps[t]*expf(0.5f*lv);
  }
  __syncthreads();
  if(t<HH){
    float a=decb[t];
    for(int k=0;k<LATD;k++) a += z[k]*decW[k*HH+t];
    hd[t]=fmaxf(a,0.f);
  }
  __syncthreads();
  if(t<HH){
    float a=ab1[t];
    for(int k=0;k<HH;k++) a += hd[k]*aW1[k*HH+t];
    t1[t]=fmaxf(a,0.f);
  } else {
    int j=t-HH;
    float a=nb1[j];
    for(int k=0;k<HH;k++) a += hd[k]*nW1[k*HH+j];
    t2[j]=fmaxf(a,0.f);
  }
  __syncthreads();
  for(int j=t;j<MAXNN;j+=256){
    float a=ab2[j];
    for(int k=0;k<HH;k++) a += t1[k]*aW2[k*MAXNN+j];
    rowadj[j]=a;
  }
  if(t<HH){
    float a=nb2[t];
    for(int k=0;k<HH;k++) a += t2[k]*nW2[k*HH+t];
    rownodes[t]=a;
  }
}

// ---------------- broadcast the two decoder rows over all N nodes ----------------
__global__ __launch_bounds__(256) void kbcast(const float* __restrict__ rowadj,
                                              const float* __restrict__ rownodes,
                                              float* __restrict__ out){
  __shared__ float row[MAXNN+HH];
  int t=threadIdx.x;
  if(t<MAXNN) row[t]=rowadj[t];
  if(t<HH) row[MAXNN+t]=rownodes[t];
  __syncthreads();
  int stride=gridDim.x*blockDim.x;
  for(int idx=blockIdx.x*blockDim.x+t; idx<OUT_TOT; idx+=stride){
    if(idx<ADJ_TOT) out[idx]=row[idx%MAXNN];
    else { int j=(idx-ADJ_TOT)&(HH-1); out[idx]=row[MAXNN+j]; }
  }
}

extern "C" void kernel_launch(void* const* d_in, const int* in_sizes, int n_in,
                              void* d_out, int out_size, void* d_ws, size_t ws_size,
                              hipStream_t stream){
  const float* x   = (const float*)d_in[0];
  const int*   ei  = (const int*)d_in[1];
  const float* ea  = (const float*)d_in[2];
  const float* eps = (const float*)d_in[3];
  const float* W1  =(const float*)d_in[5];
  const float* as1 =(const float*)d_in[6];
  const float* ad1 =(const float*)d_in[7];
  const float* We1 =(const float*)d_in[8];
  const float* ae1 =(const float*)d_in[9];
  const float* b1  =(const float*)d_in[10];
  const float* W2  =(const float*)d_in[11];
  const float* as2 =(const float*)d_in[12];
  const float* ad2 =(const float*)d_in[13];
  const float* We2 =(const float*)d_in[14];
  const float* ae2 =(const float*)d_in[15];
  const float* b2  =(const float*)d_in[16];
  const float* muW =(const float*)d_in[17];
  const float* mub =(const float*)d_in[18];
  const float* lvW =(const float*)d_in[19];
  const float* lvb =(const float*)d_in[20];
  const float* decW=(const float*)d_in[21];
  const float* decb=(const float*)d_in[22];
  const float* aW1 =(const float*)d_in[23];
  const float* ab1 =(const float*)d_in[24];
  const float* aW2 =(const float*)d_in[25];
  const float* ab2 =(const float*)d_in[26];
  const float* nW1 =(const float*)d_in[27];
  const float* nb1 =(const float*)d_in[28];
  const float* nW2 =(const float*)d_in[29];
  const float* nb2 =(const float*)d_in[30];
  float* out=(float*)d_out;

  char* w=(char*)d_ws;
  unsigned short* Abf = (unsigned short*)w; w += (size_t)NN*HH*2;
  float*  Bb       = (float*)w;  w += (size_t)NN*HH*4;
  float4* csr      = (float4*)w; w += (size_t)EF*16;
  float*  alphabuf = (float*)w;  w += (size_t)EF*4;
  int*    srcbuf   = (int*)w;    w += (size_t)EF*4;
  int*    erank    = (int*)w;    w += (size_t)EE*4;
  int*    rowstart = (int*)w;    w += (size_t)(NN+1)*4;
  int*    ideg     = (int*)w;    w += (size_t)NN*4;
  float*  asrc     = (float*)w;  w += (size_t)NN*4;
  float*  adst     = (float*)w;  w += (size_t)NN*4;
  float*  hgsum    = (float*)w;  w += 128*4;
  float*  wa1      = (float*)w;  w += 16*4;
  float*  wa2      = (float*)w;  w += 16*4;
  float*  rowadj   = (float*)w;  w += 256*4;
  float*  rownodes = (float*)w;  w += 128*4;
  int*    blocksum = (int*)w;    w += 64*4;
  int*    blockoff = (int*)w;    w += 64*4;

  int nb = (NN+1023)/1024; // 49
  int gemmblocks = (NN+63)/64;   // 782
  int gatblocks  = (NN+3)/4;     // 12500

  hipLaunchKernelGGL(kinit, dim3((NN+255)/256), dim3(256), 0, stream, ideg, hgsum);
  hipLaunchKernelGGL(kwa, dim3(1), dim3(64), 0, stream, We1, ae1, We2, ae2, wa1, wa2);
  hipLaunchKernelGGL(kdeg, dim3((EE+255)/256), dim3(256), 0, stream, ei, ideg, erank);
  hipLaunchKernelGGL(kscan1, dim3(nb), dim3(1024), 0, stream, ideg, rowstart, blocksum);
  hipLaunchKernelGGL(kscan2, dim3(1), dim3(64), 0, stream, blocksum, blockoff, nb);
  hipLaunchKernelGGL(kscan3, dim3((NN+255)/256), dim3(256), 0, stream, rowstart, blockoff, nb);
  hipLaunchKernelGGL(kscatter, dim3((EE+255)/256), dim3(256), 0, stream,
                     ei, ea, wa1, wa2, rowstart, erank, csr);
  hipLaunchKernelGGL(kself, dim3((NN+15)/16), dim3(256), 0, stream, rowstart, ideg, csr);
  // layer 1
  hipLaunchKernelGGL(kgemm2, dim3(gemmblocks), dim3(256), 0, stream, x,  W1, as1, ad1, Abf, asrc, adst);
  hipLaunchKernelGGL(kgat,  dim3(gatblocks), dim3(256), 0, stream, Abf, asrc, adst, rowstart, csr, 0, b1, alphabuf, srcbuf, Bb);
  // layer 2
  hipLaunchKernelGGL(kgemm2, dim3(gemmblocks), dim3(256), 0, stream, Bb, W2, as2, ad2, Abf, asrc, adst);
  hipLaunchKernelGGL(kgat,  dim3(gatblocks), dim3(256), 0, stream, Abf, asrc, adst, rowstart, csr, 1, b2, alphabuf, srcbuf, Bb);
  // graph embedding + decoder + broadcast
  hipLaunchKernelGGL(khg,   dim3(512), dim3(256), 0, stream, Bb, hgsum);
  hipLaunchKernelGGL(kdec,  dim3(1), dim3(256), 0, stream, hgsum, eps,
                     muW,mub,lvW,lvb,decW,decb,aW1,ab1,aW2,ab2,nW1,nb1,nW2,nb2,
                     out, rowadj, rownodes);
  hipLaunchKernelGGL(kbcast, dim3(2048), dim3(256), 0, stream, rowadj, rownodes, out);
}

// Round 9
// 453.528 us; speedup vs baseline: 1.0707x; 1.0707x over previous
//
#include <hip/hip_runtime.h>
#include <math.h>

#define NN   50000
#define EE   800000
#define EF   850000   // EE + NN self loops
#define HH   128
#define FE   16
#define LATD 64
#define MAXNN 200

#define ADJ_TOT   10000000   // NN*MAXNN
#define NODES_TOT 6400000    // NN*HH
#define OUT_TOT   16400000   // ADJ_TOT + NODES_TOT
#define MU_OFF    16400000
#define LV_OFF    16400064

typedef __attribute__((ext_vector_type(8))) short bf16x8;
typedef __attribute__((ext_vector_type(4))) float f32x4;

__device__ __forceinline__ unsigned short f2bf(float f){
  unsigned int u = __float_as_uint(f);
  unsigned int r = (u + 0x7FFFu + ((u>>16)&1u)) >> 16;   // RNE
  return (unsigned short)r;
}
__device__ __forceinline__ float bf2f(unsigned short h){
  return __uint_as_float(((unsigned int)h)<<16);
}

// ---------------- init ----------------
__global__ void kinit(int* ideg, float* hgsum){
  int i = blockIdx.x*blockDim.x + threadIdx.x;
  if(i < NN) ideg[i]=0;
  if(i < HH) hgsum[i]=0.f;
}

// wa[f] = sum_j We[f][j]*att_e[j]   (fold edge-MLP into 16-vector)
__global__ void kwa(const float* We1, const float* ae1, const float* We2, const float* ae2,
                    float* wa1, float* wa2){
  int t = threadIdx.x;
  if(t < FE){
    float s1=0.f, s2=0.f;
    for(int j=0;j<HH;j++){ s1 += We1[t*HH+j]*ae1[j]; s2 += We2[t*HH+j]*ae2[j]; }
    wa1[t]=s1; wa2[t]=s2;
  }
}

// pack W -> transposed bf16 Wp[n][k]
__global__ void kwprep(const float* __restrict__ W1, const float* __restrict__ W2,
                       unsigned short* __restrict__ Wp1, unsigned short* __restrict__ Wp2){
  int t = blockIdx.x*256 + threadIdx.x;
  if(t < HH*HH){
    int n = t >> 7, k = t & 127;
    Wp1[t] = f2bf(W1[k*HH + n]);
    Wp2[t] = f2bf(W2[k*HH + n]);
  }
}

// degree count + within-row rank (atomic return) — removes the atomic from kscatter
__global__ void kdeg(const int* __restrict__ ei, int* ideg, int* __restrict__ erank){
  int e = blockIdx.x*blockDim.x + threadIdx.x;
  if(e<EE) erank[e] = atomicAdd(&ideg[ei[EE+e]], 1);
}

// ---------------- exclusive scan of rowlen = ideg+1 ----------------
__global__ void kscan1(const int* __restrict__ ideg, int* rowstart, int* blocksum){
  __shared__ int sd[1024];
  int t=threadIdx.x; int i=blockIdx.x*1024+t;
  int v = (i<NN)? (ideg[i]+1) : 0;
  sd[t]=v; __syncthreads();
  for(int off=1; off<1024; off<<=1){
    int x = (t>=off)? sd[t-off] : 0;
    __syncthreads();
    sd[t] += x;
    __syncthreads();
  }
  if(i<NN) rowstart[i] = sd[t]-v;
  if(t==1023) blocksum[blockIdx.x]=sd[1023];
}
__global__ void kscan2(const int* blocksum, int* blockoff, int nb){
  if(threadIdx.x==0){
    int run=0;
    for(int b=0;b<nb;b++){ blockoff[b]=run; run+=blocksum[b]; }
    blockoff[nb]=run;
  }
}
__global__ void kscan3(int* rowstart, const int* __restrict__ blockoff, int nb){
  int i=blockIdx.x*blockDim.x+threadIdx.x;
  if(i<NN) rowstart[i]+=blockoff[i>>10];
  if(i==0) rowstart[NN]=blockoff[nb];
}

// ---------------- CSR scatter: one packed 16B entry per edge, NO atomic ----------------
__global__ void kscatter(const int* __restrict__ ei, const float* __restrict__ ea,
                         const float* __restrict__ wa1, const float* __restrict__ wa2,
                         const int* __restrict__ rowstart, const int* __restrict__ erank,
                         float4* __restrict__ csr){
  int e=blockIdx.x*blockDim.x+threadIdx.x;
  if(e>=EE) return;
  int s=ei[e], d=ei[EE+e];
  const float4* ea4 = (const float4*)(ea + (size_t)e*FE);
  float4 v0=ea4[0], v1=ea4[1], v2=ea4[2], v3=ea4[3];
  float va[16]={v0.x,v0.y,v0.z,v0.w, v1.x,v1.y,v1.z,v1.w,
                v2.x,v2.y,v2.z,v2.w, v3.x,v3.y,v3.z,v3.w};
  float d1=0.f,d2=0.f;
  #pragma unroll
  for(int f=0;f<FE;f++){ d1+=va[f]*wa1[f]; d2+=va[f]*wa2[f]; }
  int pos = rowstart[d] + erank[e];
  csr[pos] = make_float4(__int_as_float(s), d1, d2, 0.f);
}

// self-loop entry: et = mean of row's et values (16-lane group per node)
__global__ __launch_bounds__(256) void kself(const int* __restrict__ rowstart,
                      const int* __restrict__ ideg,
                      float4* __restrict__ csr){
  int tid = threadIdx.x;
  int l16 = tid & 15;
  int grp = tid >> 4;
  int i = blockIdx.x*16 + grp;
  if(i>=NN) return;
  int base = rowstart[i]; int deg = ideg[i];
  float s1=0.f, s2=0.f;
  for(int k=l16;k<deg;k+=16){ float4 en=csr[base+k]; s1+=en.y; s2+=en.z; }
  #pragma unroll
  for(int m=8;m>=1;m>>=1){ s1+=__shfl_xor(s1,m,16); s2+=__shfl_xor(s2,m,16); }
  if(l16==0){
    float dg = (float)deg; if(dg<1.f) dg=1.f;
    csr[base+deg] = make_float4(__int_as_float(i), s1/dg, s2/dg, 0.f);
  }
}

// ---------------- MFMA GEMM: Gbf = bf16( h @ W ), fused asrc/adst ----------------
// one wave per 16 rows; 8 col-tiles of 16; K-loop 4 x mfma 16x16x32 bf16.
// A frag: A[m=lane&15][k=quad*8+j]; B frag from Wp[n][k]; C/D: col=lane&15,row=quad*4+reg.
__global__ __launch_bounds__(256) void kgemm3(const void* __restrict__ hin, int h_is_fp32,
    const unsigned short* __restrict__ Wp,
    const float* __restrict__ atts, const float* __restrict__ attd,
    unsigned short* __restrict__ Gbf, float* __restrict__ asrc, float* __restrict__ adst){
  int lane = threadIdx.x & 63;
  int wid  = threadIdx.x >> 6;
  int l = lane & 15, q = lane >> 4;
  int r0 = blockIdx.x*64 + wid*16;
  if(r0 >= NN) return;                 // 50000 % 16 == 0: whole wave valid or not
  const unsigned short* hb = (const unsigned short*)hin;
  const float*          hf = (const float*)hin;
  int row = r0 + l;

  f32x4 acc[8];
  #pragma unroll
  for(int t=0;t<8;t++) acc[t]=(f32x4){0.f,0.f,0.f,0.f};

  #pragma unroll
  for(int kb=0;kb<4;kb++){
    bf16x8 a;
    if(h_is_fp32){
      const float* p = hf + (size_t)row*HH + kb*32 + q*8;
      float4 u0 = *(const float4*)(p);
      float4 u1 = *(const float4*)(p+4);
      a[0]=(short)f2bf(u0.x); a[1]=(short)f2bf(u0.y); a[2]=(short)f2bf(u0.z); a[3]=(short)f2bf(u0.w);
      a[4]=(short)f2bf(u1.x); a[5]=(short)f2bf(u1.y); a[6]=(short)f2bf(u1.z); a[7]=(short)f2bf(u1.w);
    } else {
      a = *(const bf16x8*)(hb + (size_t)row*HH + kb*32 + q*8);
    }
    #pragma unroll
    for(int t=0;t<8;t++){
      bf16x8 b = *(const bf16x8*)(Wp + (size_t)(t*16+l)*HH + kb*32 + q*8);
      acc[t] = __builtin_amdgcn_mfma_f32_16x16x32_bf16(a, b, acc[t], 0,0,0);
    }
  }

  // fused row-dots: reduce over l (16 lanes)
  float av[8], dv[8];
  #pragma unroll
  for(int t=0;t<8;t++){ av[t]=atts[t*16+l]; dv[t]=attd[t*16+l]; }
  #pragma unroll
  for(int reg=0;reg<4;reg++){
    float ps=0.f, pd=0.f;
    #pragma unroll
    for(int t=0;t<8;t++){ ps+=acc[t][reg]*av[t]; pd+=acc[t][reg]*dv[t]; }
    #pragma unroll
    for(int m=8;m>=1;m>>=1){ ps+=__shfl_xor(ps,m,16); pd+=__shfl_xor(pd,m,16); }
    if(l==0){ int R=r0+q*4+reg; asrc[R]=ps; adst[R]=pd; }
  }
  // store G as bf16 (2B scattered; L2 merges — rows fully written by this wave)
  #pragma unroll
  for(int t=0;t<8;t++)
    #pragma unroll
    for(int reg=0;reg<4;reg++)
      Gbf[(size_t)(r0+q*4+reg)*HH + t*16 + l] = f2bf(acc[t][reg]);
}

// ---------------- GAT softmax-aggregate: ONE WAVE per dst node, bf16 out ----
__global__ __launch_bounds__(256) void kgat(const unsigned short* __restrict__ A,
    const float* __restrict__ asrc, const float* __restrict__ adst,
    const int* __restrict__ rowstart, const float4* __restrict__ csr,
    int etsel, const float* __restrict__ bias,
    float* __restrict__ alphabuf, int* __restrict__ srcbuf,
    unsigned short* __restrict__ Bout){
  int lane = threadIdx.x & 63;
  int wid  = threadIdx.x >> 6;
  int i = blockIdx.x*4 + wid;
  if(i >= NN) return;
  int base = rowstart[i]; int len = rowstart[i+1]-base;
  float adi = adst[i];
  float acc0=0.f, acc1=0.f;
  float den;
  if(__builtin_expect(len <= 64, 1)){
    float a = -1e30f; int s=0;
    if(lane < len){
      float4 en = csr[base+lane];
      s = __float_as_int(en.x);
      float et = etsel ? en.z : en.y;
      a = asrc[s] + adi + et;
      a = a>0.f ? a : 0.2f*a;            // leaky_relu 0.2
    }
    float m = a;
    #pragma unroll
    for(int mk=32;mk>=1;mk>>=1) m = fmaxf(m, __shfl_xor(m, mk));
    float ex = (lane<len) ? __expf(a-m) : 0.f;
    float sm = ex;
    #pragma unroll
    for(int mk=32;mk>=1;mk>>=1) sm += __shfl_xor(sm, mk);
    den = sm;
    const unsigned short* Ap = A + lane*2;
    int k=0;
    for(; k+4<=len; k+=4){
      float wk0=__shfl(ex,k+0); int sk0=__shfl(s,k+0);
      float wk1=__shfl(ex,k+1); int sk1=__shfl(s,k+1);
      float wk2=__shfl(ex,k+2); int sk2=__shfl(s,k+2);
      float wk3=__shfl(ex,k+3); int sk3=__shfl(s,k+3);
      unsigned p0 = *(const unsigned*)(Ap + (size_t)sk0*HH);
      unsigned p1 = *(const unsigned*)(Ap + (size_t)sk1*HH);
      unsigned p2 = *(const unsigned*)(Ap + (size_t)sk2*HH);
      unsigned p3 = *(const unsigned*)(Ap + (size_t)sk3*HH);
      acc0 += wk0 * __uint_as_float(p0<<16);
      acc1 += wk0 * __uint_as_float(p0 & 0xFFFF0000u);
      acc0 += wk1 * __uint_as_float(p1<<16);
      acc1 += wk1 * __uint_as_float(p1 & 0xFFFF0000u);
      acc0 += wk2 * __uint_as_float(p2<<16);
      acc1 += wk2 * __uint_as_float(p2 & 0xFFFF0000u);
      acc0 += wk3 * __uint_as_float(p3<<16);
      acc1 += wk3 * __uint_as_float(p3 & 0xFFFF0000u);
    }
    for(; k<len; k++){
      float wk = __shfl(ex, k);
      int   sk = __shfl(s, k);
      unsigned pr = *(const unsigned*)(Ap + (size_t)sk*HH);
      acc0 += wk * __uint_as_float(pr<<16);
      acc1 += wk * __uint_as_float(pr & 0xFFFF0000u);
    }
  } else {
    // rare fallback: strided two-pass with global spill
    float lm = -1e30f;
    for(int k=lane;k<len;k+=64){
      float4 en = csr[base+k];
      int s = __float_as_int(en.x);
      float et = etsel ? en.z : en.y;
      float a = asrc[s] + adi + et;
      a = a>0.f ? a : 0.2f*a;
      alphabuf[base+k]=a; srcbuf[base+k]=s;
      lm = fmaxf(lm,a);
    }
    #pragma unroll
    for(int mk=32;mk>=1;mk>>=1) lm = fmaxf(lm, __shfl_xor(lm, mk));
    float ls=0.f;
    for(int k=lane;k<len;k+=64){
      float ex = __expf(alphabuf[base+k]-lm);
      alphabuf[base+k]=ex; ls+=ex;
    }
    #pragma unroll
    for(int mk=32;mk>=1;mk>>=1) ls += __shfl_xor(ls, mk);
    den = ls;
    for(int c=0;c<len;c+=64){
      int kk = c+lane;
      float w = (kk<len)? alphabuf[base+kk] : 0.f;
      int   s = (kk<len)? srcbuf[base+kk] : 0;
      int lim = min(64, len-c);
      for(int j=0;j<lim;j++){
        float wk = __shfl(w, j);
        int   sk = __shfl(s, j);
        unsigned pr = *(const unsigned*)(A + (size_t)sk*HH + lane*2);
        acc0 += wk * __uint_as_float(pr<<16);
        acc1 += wk * __uint_as_float(pr & 0xFFFF0000u);
      }
    }
  }
  float inv = 1.f/den;
  float2 bb = *(const float2*)(bias + lane*2);
  float ox = fmaxf(acc0*inv + bb.x, 0.f);
  float oy = fmaxf(acc1*inv + bb.y, 0.f);
  unsigned ov = (unsigned)f2bf(ox) | ((unsigned)f2bf(oy)<<16);
  *(unsigned*)(Bout + (size_t)i*HH + lane*2) = ov;
}

// ---------------- column mean (bf16 input): grid-strided, 512 blocks ----------------
__global__ __launch_bounds__(256) void khg(const unsigned short* __restrict__ B, float* hgsum){
  int f = threadIdx.x & 127;      // column
  int half = threadIdx.x >> 7;    // 0/1
  float s=0.f;
  for(int i = blockIdx.x*2+half; i < NN; i += gridDim.x*2)
    s += bf2f(B[(size_t)i*HH + f]);
  __shared__ float sd[256];
  sd[threadIdx.x]=s; __syncthreads();
  if(half==0) atomicAdd(&hgsum[f], sd[threadIdx.x]+sd[threadIdx.x+128]);
}

// ---------------- tiny decoder, single block ----------------
__global__ __launch_bounds__(256) void kdec(const float* __restrict__ hgsum, const float* __restrict__ eps,
   const float* muW,const float* mub,const float* lvW,const float* lvb,
   const float* decW,const float* decb,
   const float* aW1,const float* ab1,const float* aW2,const float* ab2,
   const float* nW1,const float* nb1,const float* nW2,const float* nb2,
   float* out, float* rowadj, float* rownodes){
  __shared__ float hg[HH], z[LATD], hd[HH], t1[HH], t2[HH];
  int t=threadIdx.x;
  if(t<HH) hg[t]=hgsum[t]*(1.0f/NN);
  __syncthreads();
  if(t<LATD){
    float mu=mub[t], lv=lvb[t];
    for(int k=0;k<HH;k++){ mu += hg[k]*muW[k*LATD+t]; lv += hg[k]*lvW[k*LATD+t]; }
    out[MU_OFF+t]=mu; out[LV_OFF+t]=lv;
    z[t]=mu + eps[t]*expf(0.5f*lv);
  }
  __syncthreads();
  if(t<HH){
    float a=decb[t];
    for(int k=0;k<LATD;k++) a += z[k]*decW[k*HH+t];
    hd[t]=fmaxf(a,0.f);
  }
  __syncthreads();
  if(t<HH){
    float a=ab1[t];
    for(int k=0;k<HH;k++) a += hd[k]*aW1[k*HH+t];
    t1[t]=fmaxf(a,0.f);
  } else {
    int j=t-HH;
    float a=nb1[j];
    for(int k=0;k<HH;k++) a += hd[k]*nW1[k*HH+j];
    t2[j]=fmaxf(a,0.f);
  }
  __syncthreads();
  for(int j=t;j<MAXNN;j+=256){
    float a=ab2[j];
    for(int k=0;k<HH;k++) a += t1[k]*aW2[k*MAXNN+j];
    rowadj[j]=a;
  }
  if(t<HH){
    float a=nb2[t];
    for(int k=0;k<HH;k++) a += t2[k]*nW2[k*HH+t];
    rownodes[t]=a;
  }
}

// ---------------- broadcast the two decoder rows over all N nodes ----------------
__global__ __launch_bounds__(256) void kbcast(const float* __restrict__ rowadj,
                                              const float* __restrict__ rownodes,
                                              float* __restrict__ out){
  __shared__ float row[MAXNN+HH];
  int t=threadIdx.x;
  if(t<MAXNN) row[t]=rowadj[t];
  if(t<HH) row[MAXNN+t]=rownodes[t];
  __syncthreads();
  int stride=gridDim.x*blockDim.x;
  for(int idx=blockIdx.x*blockDim.x+t; idx<OUT_TOT; idx+=stride){
    if(idx<ADJ_TOT) out[idx]=row[idx%MAXNN];
    else { int j=(idx-ADJ_TOT)&(HH-1); out[idx]=row[MAXNN+j]; }
  }
}

extern "C" void kernel_launch(void* const* d_in, const int* in_sizes, int n_in,
                              void* d_out, int out_size, void* d_ws, size_t ws_size,
                              hipStream_t stream){
  const float* x   = (const float*)d_in[0];
  const int*   ei  = (const int*)d_in[1];
  const float* ea  = (const float*)d_in[2];
  const float* eps = (const float*)d_in[3];
  const float* W1  =(const float*)d_in[5];
  const float* as1 =(const float*)d_in[6];
  const float* ad1 =(const float*)d_in[7];
  const float* We1 =(const float*)d_in[8];
  const float* ae1 =(const float*)d_in[9];
  const float* b1  =(const float*)d_in[10];
  const float* W2  =(const float*)d_in[11];
  const float* as2 =(const float*)d_in[12];
  const float* ad2 =(const float*)d_in[13];
  const float* We2 =(const float*)d_in[14];
  const float* ae2 =(const float*)d_in[15];
  const float* b2  =(const float*)d_in[16];
  const float* muW =(const float*)d_in[17];
  const float* mub =(const float*)d_in[18];
  const float* lvW =(const float*)d_in[19];
  const float* lvb =(const float*)d_in[20];
  const float* decW=(const float*)d_in[21];
  const float* decb=(const float*)d_in[22];
  const float* aW1 =(const float*)d_in[23];
  const float* ab1 =(const float*)d_in[24];
  const float* aW2 =(const float*)d_in[25];
  const float* ab2 =(const float*)d_in[26];
  const float* nW1 =(const float*)d_in[27];
  const float* nb1 =(const float*)d_in[28];
  const float* nW2 =(const float*)d_in[29];
  const float* nb2 =(const float*)d_in[30];
  float* out=(float*)d_out;

  char* w=(char*)d_ws;
  unsigned short* Abf = (unsigned short*)w; w += (size_t)NN*HH*2;
  unsigned short* Bbf = (unsigned short*)w; w += (size_t)NN*HH*2;
  unsigned short* Wp1 = (unsigned short*)w; w += (size_t)HH*HH*2;
  unsigned short* Wp2 = (unsigned short*)w; w += (size_t)HH*HH*2;
  float4* csr      = (float4*)w; w += (size_t)EF*16;
  float*  alphabuf = (float*)w;  w += (size_t)EF*4;
  int*    srcbuf   = (int*)w;    w += (size_t)EF*4;
  int*    erank    = (int*)w;    w += (size_t)EE*4;
  int*    rowstart = (int*)w;    w += (size_t)(NN+1)*4;
  int*    ideg     = (int*)w;    w += (size_t)NN*4;
  float*  asrc     = (float*)w;  w += (size_t)NN*4;
  float*  adst     = (float*)w;  w += (size_t)NN*4;
  float*  hgsum    = (float*)w;  w += 128*4;
  float*  wa1      = (float*)w;  w += 16*4;
  float*  wa2      = (float*)w;  w += 16*4;
  float*  rowadj   = (float*)w;  w += 256*4;
  float*  rownodes = (float*)w;  w += 128*4;
  int*    blocksum = (int*)w;    w += 64*4;
  int*    blockoff = (int*)w;    w += 64*4;

  int nb = (NN+1023)/1024; // 49
  int gemmblocks = (NN+63)/64;   // 782
  int gatblocks  = (NN+3)/4;     // 12500

  hipLaunchKernelGGL(kinit, dim3((NN+255)/256), dim3(256), 0, stream, ideg, hgsum);
  hipLaunchKernelGGL(kwa, dim3(1), dim3(64), 0, stream, We1, ae1, We2, ae2, wa1, wa2);
  hipLaunchKernelGGL(kwprep, dim3((HH*HH+255)/256), dim3(256), 0, stream, W1, W2, Wp1, Wp2);
  hipLaunchKernelGGL(kdeg, dim3((EE+255)/256), dim3(256), 0, stream, ei, ideg, erank);
  hipLaunchKernelGGL(kscan1, dim3(nb), dim3(1024), 0, stream, ideg, rowstart, blocksum);
  hipLaunchKernelGGL(kscan2, dim3(1), dim3(64), 0, stream, blocksum, blockoff, nb);
  hipLaunchKernelGGL(kscan3, dim3((NN+255)/256), dim3(256), 0, stream, rowstart, blockoff, nb);
  hipLaunchKernelGGL(kscatter, dim3((EE+255)/256), dim3(256), 0, stream,
                     ei, ea, wa1, wa2, rowstart, erank, csr);
  hipLaunchKernelGGL(kself, dim3((NN+15)/16), dim3(256), 0, stream, rowstart, ideg, csr);
  // layer 1 (fp32 x input)
  hipLaunchKernelGGL(kgemm3, dim3(gemmblocks), dim3(256), 0, stream,
                     (const void*)x, 1, Wp1, as1, ad1, Abf, asrc, adst);
  hipLaunchKernelGGL(kgat,  dim3(gatblocks), dim3(256), 0, stream, Abf, asrc, adst, rowstart, csr, 0, b1, alphabuf, srcbuf, Bbf);
  // layer 2 (bf16 input)
  hipLaunchKernelGGL(kgemm3, dim3(gemmblocks), dim3(256), 0, stream,
                     (const void*)Bbf, 0, Wp2, as2, ad2, Abf, asrc, adst);
  hipLaunchKernelGGL(kgat,  dim3(gatblocks), dim3(256), 0, stream, Abf, asrc, adst, rowstart, csr, 1, b2, alphabuf, srcbuf, Bbf);
  // graph embedding + decoder + broadcast
  hipLaunchKernelGGL(khg,   dim3(512), dim3(256), 0, stream, Bbf, hgsum);
  hipLaunchKernelGGL(kdec,  dim3(1), dim3(256), 0, stream, hgsum, eps,
                     muW,mub,lvW,lvb,decW,decb,aW1,ab1,aW2,ab2,nW1,nb1,nW2,nb2,
                     out, rowadj, rownodes);
  hipLaunchKernelGGL(kbcast, dim3(2048), dim3(256), 0, stream, rowadj, rownodes, out);
}

// Round 10
// 452.832 us; speedup vs baseline: 1.0724x; 1.0015x over previous
//
#include <hip/hip_runtime.h>
#include <math.h>

#define NN   50000
#define EE   800000
#define EF   850000   // EE + NN self loops
#define HH   128
#define FE   16
#define LATD 64
#define MAXNN 200

#define ADJ_TOT   10000000   // NN*MAXNN
#define NODES_TOT 6400000    // NN*HH
#define OUT_TOT   16400000   // ADJ_TOT + NODES_TOT
#define MU_OFF    16400000
#define LV_OFF    16400064

typedef __attribute__((ext_vector_type(8))) short bf16x8;
typedef __attribute__((ext_vector_type(4))) float f32x4;

__device__ __forceinline__ unsigned short f2bf(float f){
  unsigned int u = __float_as_uint(f);
  unsigned int r = (u + 0x7FFFu + ((u>>16)&1u)) >> 16;   // RNE
  return (unsigned short)r;
}
__device__ __forceinline__ float bf2f(unsigned short h){
  return __uint_as_float(((unsigned int)h)<<16);
}
__device__ __forceinline__ float bflo(unsigned u){ return __uint_as_float(u<<16); }
__device__ __forceinline__ float bfhi(unsigned u){ return __uint_as_float(u & 0xFFFF0000u); }

// ---------------- init ----------------
__global__ void kinit(int* ideg, float* hgsum){
  int i = blockIdx.x*blockDim.x + threadIdx.x;
  if(i < NN) ideg[i]=0;
  if(i < HH) hgsum[i]=0.f;
}

// wa[f] = sum_j We[f][j]*att_e[j]   (fold edge-MLP into 16-vector)
__global__ void kwa(const float* We1, const float* ae1, const float* We2, const float* ae2,
                    float* wa1, float* wa2){
  int t = threadIdx.x;
  if(t < FE){
    float s1=0.f, s2=0.f;
    for(int j=0;j<HH;j++){ s1 += We1[t*HH+j]*ae1[j]; s2 += We2[t*HH+j]*ae2[j]; }
    wa1[t]=s1; wa2[t]=s2;
  }
}

// pack W -> transposed bf16 Wp[n][k]
__global__ void kwprep(const float* __restrict__ W1, const float* __restrict__ W2,
                       unsigned short* __restrict__ Wp1, unsigned short* __restrict__ Wp2){
  int t = blockIdx.x*256 + threadIdx.x;
  if(t < HH*HH){
    int n = t >> 7, k = t & 127;
    Wp1[t] = f2bf(W1[k*HH + n]);
    Wp2[t] = f2bf(W2[k*HH + n]);
  }
}

// degree count + within-row rank (atomic return) — removes the atomic from kscatter
__global__ void kdeg(const int* __restrict__ ei, int* ideg, int* __restrict__ erank){
  int e = blockIdx.x*blockDim.x + threadIdx.x;
  if(e<EE) erank[e] = atomicAdd(&ideg[ei[EE+e]], 1);
}

// ---------------- exclusive scan of rowlen = ideg+1 ----------------
__global__ void kscan1(const int* __restrict__ ideg, int* rowstart, int* blocksum){
  __shared__ int sd[1024];
  int t=threadIdx.x; int i=blockIdx.x*1024+t;
  int v = (i<NN)? (ideg[i]+1) : 0;
  sd[t]=v; __syncthreads();
  for(int off=1; off<1024; off<<=1){
    int x = (t>=off)? sd[t-off] : 0;
    __syncthreads();
    sd[t] += x;
    __syncthreads();
  }
  if(i<NN) rowstart[i] = sd[t]-v;
  if(t==1023) blocksum[blockIdx.x]=sd[1023];
}
__global__ void kscan2(const int* blocksum, int* blockoff, int nb){
  if(threadIdx.x==0){
    int run=0;
    for(int b=0;b<nb;b++){ blockoff[b]=run; run+=blocksum[b]; }
    blockoff[nb]=run;
  }
}
__global__ void kscan3(int* rowstart, const int* __restrict__ blockoff, int nb){
  int i=blockIdx.x*blockDim.x+threadIdx.x;
  if(i<NN) rowstart[i]+=blockoff[i>>10];
  if(i==0) rowstart[NN]=blockoff[nb];
}

// ---------------- CSR scatter: one packed 16B entry per edge, NO atomic ----------------
__global__ void kscatter(const int* __restrict__ ei, const float* __restrict__ ea,
                         const float* __restrict__ wa1, const float* __restrict__ wa2,
                         const int* __restrict__ rowstart, const int* __restrict__ erank,
                         float4* __restrict__ csr){
  int e=blockIdx.x*blockDim.x+threadIdx.x;
  if(e>=EE) return;
  int s=ei[e], d=ei[EE+e];
  const float4* ea4 = (const float4*)(ea + (size_t)e*FE);
  float4 v0=ea4[0], v1=ea4[1], v2=ea4[2], v3=ea4[3];
  float va[16]={v0.x,v0.y,v0.z,v0.w, v1.x,v1.y,v1.z,v1.w,
                v2.x,v2.y,v2.z,v2.w, v3.x,v3.y,v3.z,v3.w};
  float d1=0.f,d2=0.f;
  #pragma unroll
  for(int f=0;f<FE;f++){ d1+=va[f]*wa1[f]; d2+=va[f]*wa2[f]; }
  int pos = rowstart[d] + erank[e];
  csr[pos] = make_float4(__int_as_float(s), d1, d2, 0.f);
}

// self-loop entry: et = mean of row's et values (16-lane group per node)
__global__ __launch_bounds__(256) void kself(const int* __restrict__ rowstart,
                      const int* __restrict__ ideg,
                      float4* __restrict__ csr){
  int tid = threadIdx.x;
  int l16 = tid & 15;
  int grp = tid >> 4;
  int i = blockIdx.x*16 + grp;
  if(i>=NN) return;
  int base = rowstart[i]; int deg = ideg[i];
  float s1=0.f, s2=0.f;
  for(int k=l16;k<deg;k+=16){ float4 en=csr[base+k]; s1+=en.y; s2+=en.z; }
  #pragma unroll
  for(int m=8;m>=1;m>>=1){ s1+=__shfl_xor(s1,m,16); s2+=__shfl_xor(s2,m,16); }
  if(l16==0){
    float dg = (float)deg; if(dg<1.f) dg=1.f;
    csr[base+deg] = make_float4(__int_as_float(i), s1/dg, s2/dg, 0.f);
  }
}

// ---------------- MFMA GEMM: Gbf = bf16( h @ W ), fused asrc/adst ----------------
__global__ __launch_bounds__(256) void kgemm3(const void* __restrict__ hin, int h_is_fp32,
    const unsigned short* __restrict__ Wp,
    const float* __restrict__ atts, const float* __restrict__ attd,
    unsigned short* __restrict__ Gbf, float* __restrict__ asrc, float* __restrict__ adst){
  int lane = threadIdx.x & 63;
  int wid  = threadIdx.x >> 6;
  int l = lane & 15, q = lane >> 4;
  int r0 = blockIdx.x*64 + wid*16;
  if(r0 >= NN) return;
  const unsigned short* hb = (const unsigned short*)hin;
  const float*          hf = (const float*)hin;
  int row = r0 + l;

  f32x4 acc[8];
  #pragma unroll
  for(int t=0;t<8;t++) acc[t]=(f32x4){0.f,0.f,0.f,0.f};

  #pragma unroll
  for(int kb=0;kb<4;kb++){
    bf16x8 a;
    if(h_is_fp32){
      const float* p = hf + (size_t)row*HH + kb*32 + q*8;
      float4 u0 = *(const float4*)(p);
      float4 u1 = *(const float4*)(p+4);
      a[0]=(short)f2bf(u0.x); a[1]=(short)f2bf(u0.y); a[2]=(short)f2bf(u0.z); a[3]=(short)f2bf(u0.w);
      a[4]=(short)f2bf(u1.x); a[5]=(short)f2bf(u1.y); a[6]=(short)f2bf(u1.z); a[7]=(short)f2bf(u1.w);
    } else {
      a = *(const bf16x8*)(hb + (size_t)row*HH + kb*32 + q*8);
    }
    #pragma unroll
    for(int t=0;t<8;t++){
      bf16x8 b = *(const bf16x8*)(Wp + (size_t)(t*16+l)*HH + kb*32 + q*8);
      acc[t] = __builtin_amdgcn_mfma_f32_16x16x32_bf16(a, b, acc[t], 0,0,0);
    }
  }

  // fused row-dots: reduce over l (16 lanes)
  float av[8], dv[8];
  #pragma unroll
  for(int t=0;t<8;t++){ av[t]=atts[t*16+l]; dv[t]=attd[t*16+l]; }
  #pragma unroll
  for(int reg=0;reg<4;reg++){
    float ps=0.f, pd=0.f;
    #pragma unroll
    for(int t=0;t<8;t++){ ps+=acc[t][reg]*av[t]; pd+=acc[t][reg]*dv[t]; }
    #pragma unroll
    for(int m=8;m>=1;m>>=1){ ps+=__shfl_xor(ps,m,16); pd+=__shfl_xor(pd,m,16); }
    if(l==0){ int R=r0+q*4+reg; asrc[R]=ps; adst[R]=pd; }
  }
  #pragma unroll
  for(int t=0;t<8;t++)
    #pragma unroll
    for(int reg=0;reg<4;reg++)
      Gbf[(size_t)(r0+q*4+reg)*HH + t*16 + l] = f2bf(acc[t][reg]);
}

// ---------------- GAT softmax-aggregate: ONE WAVE per dst node ----------------
// gather: lane (lq=lane>>4, lf=lane&15) loads uint4 (8 feats) of edge c*4+lq's row
// -> one dwordx4 covers 4 edges; final shfl_xor(16/32) folds the 4 edge-subsets.
__global__ __launch_bounds__(256) void kgat(const unsigned short* __restrict__ A,
    const float* __restrict__ asrc, const float* __restrict__ adst,
    const int* __restrict__ rowstart, const float4* __restrict__ csr,
    int etsel, const float* __restrict__ bias,
    float* __restrict__ alphabuf, int* __restrict__ srcbuf,
    unsigned short* __restrict__ Bout){
  int lane = threadIdx.x & 63;
  int wid  = threadIdx.x >> 6;
  int i = blockIdx.x*4 + wid;
  if(i >= NN) return;
  int base = rowstart[i]; int len = rowstart[i+1]-base;
  int lq = lane >> 4;              // edge slot within chunk (0..3)
  int lf = lane & 15;              // feature 16B-chunk (feats lf*8 .. lf*8+7)
  float adi = adst[i];
  float den;
  float av0=0.f,av1=0.f,av2=0.f,av3=0.f,av4=0.f,av5=0.f,av6=0.f,av7=0.f;

  if(__builtin_expect(len <= 64, 1)){
    // phase 1: one edge per lane
    float a = -1e30f; int s=0;
    if(lane < len){
      float4 en = csr[base+lane];
      s = __float_as_int(en.x);
      float et = etsel ? en.z : en.y;
      a = asrc[s] + adi + et;
      a = a>0.f ? a : 0.2f*a;            // leaky_relu 0.2
    }
    float m = a;
    #pragma unroll
    for(int mk=32;mk>=1;mk>>=1) m = fmaxf(m, __shfl_xor(m, mk));
    float ex = (lane<len) ? __expf(a-m) : 0.f;
    float sm = ex;
    #pragma unroll
    for(int mk=32;mk>=1;mk>>=1) sm += __shfl_xor(sm, mk);
    den = sm;
    // phase 3: chunked gather, 2-deep pipeline
    int chunks = (len+3)>>2;
    float wk = __shfl(ex, lq);
    int   sk = __shfl(s, lq);
    uint4 p  = *((const uint4*)(A + (size_t)sk*HH) + lf);
    for(int c=0;c<chunks;c++){
      float wc = wk; uint4 pc = p;
      if(c+1<chunks){
        int idx = (c+1)*4 + lq;           // <=63 guaranteed (chunks<=16)
        wk = __shfl(ex, idx);
        sk = __shfl(s, idx);
        p  = *((const uint4*)(A + (size_t)sk*HH) + lf);
      }
      av0 += wc*bflo(pc.x); av1 += wc*bfhi(pc.x);
      av2 += wc*bflo(pc.y); av3 += wc*bfhi(pc.y);
      av4 += wc*bflo(pc.z); av5 += wc*bfhi(pc.z);
      av6 += wc*bflo(pc.w); av7 += wc*bfhi(pc.w);
    }
  } else {
    // rare fallback: strided two-pass with global spill, same chunked gather
    float lm = -1e30f;
    for(int k=lane;k<len;k+=64){
      float4 en = csr[base+k];
      int s = __float_as_int(en.x);
      float et = etsel ? en.z : en.y;
      float a = asrc[s] + adi + et;
      a = a>0.f ? a : 0.2f*a;
      alphabuf[base+k]=a; srcbuf[base+k]=s;
      lm = fmaxf(lm,a);
    }
    #pragma unroll
    for(int mk=32;mk>=1;mk>>=1) lm = fmaxf(lm, __shfl_xor(lm, mk));
    float ls=0.f;
    for(int k=lane;k<len;k+=64){
      float ex = __expf(alphabuf[base+k]-lm);
      alphabuf[base+k]=ex; ls+=ex;
    }
    #pragma unroll
    for(int mk=32;mk>=1;mk>>=1) ls += __shfl_xor(ls, mk);
    den = ls;
    int chunks = (len+3)>>2;
    for(int c=0;c<chunks;c++){
      int idx = c*4 + lq;
      float wc = (idx<len)? alphabuf[base+idx] : 0.f;
      int   sk = (idx<len)? srcbuf[base+idx] : 0;
      uint4 pc = *((const uint4*)(A + (size_t)sk*HH) + lf);
      av0 += wc*bflo(pc.x); av1 += wc*bfhi(pc.x);
      av2 += wc*bflo(pc.y); av3 += wc*bfhi(pc.y);
      av4 += wc*bflo(pc.z); av5 += wc*bfhi(pc.z);
      av6 += wc*bflo(pc.w); av7 += wc*bfhi(pc.w);
    }
  }
  // fold the 4 edge-subsets (lanes lf, lf+16, lf+32, lf+48 hold same features)
  av0 += __shfl_xor(av0,16); av0 += __shfl_xor(av0,32);
  av1 += __shfl_xor(av1,16); av1 += __shfl_xor(av1,32);
  av2 += __shfl_xor(av2,16); av2 += __shfl_xor(av2,32);
  av3 += __shfl_xor(av3,16); av3 += __shfl_xor(av3,32);
  av4 += __shfl_xor(av4,16); av4 += __shfl_xor(av4,32);
  av5 += __shfl_xor(av5,16); av5 += __shfl_xor(av5,32);
  av6 += __shfl_xor(av6,16); av6 += __shfl_xor(av6,32);
  av7 += __shfl_xor(av7,16); av7 += __shfl_xor(av7,32);
  if(lq==0){
    float inv = 1.f/den;
    float4 b0 = *(const float4*)(bias + lf*8);
    float4 b1 = *(const float4*)(bias + lf*8 + 4);
    float o0 = fmaxf(av0*inv + b0.x, 0.f);
    float o1 = fmaxf(av1*inv + b0.y, 0.f);
    float o2 = fmaxf(av2*inv + b0.z, 0.f);
    float o3 = fmaxf(av3*inv + b0.w, 0.f);
    float o4 = fmaxf(av4*inv + b1.x, 0.f);
    float o5 = fmaxf(av5*inv + b1.y, 0.f);
    float o6 = fmaxf(av6*inv + b1.z, 0.f);
    float o7 = fmaxf(av7*inv + b1.w, 0.f);
    uint4 ov;
    ov.x = (unsigned)f2bf(o0) | ((unsigned)f2bf(o1)<<16);
    ov.y = (unsigned)f2bf(o2) | ((unsigned)f2bf(o3)<<16);
    ov.z = (unsigned)f2bf(o4) | ((unsigned)f2bf(o5)<<16);
    ov.w = (unsigned)f2bf(o6) | ((unsigned)f2bf(o7)<<16);
    *((uint4*)(Bout + (size_t)i*HH) + lf) = ov;
  }
}

// ---------------- column mean (bf16 input): grid-strided, 512 blocks ----------------
__global__ __launch_bounds__(256) void khg(const unsigned short* __restrict__ B, float* hgsum){
  int f = threadIdx.x & 127;      // column
  int half = threadIdx.x >> 7;    // 0/1
  float s=0.f;
  for(int i = blockIdx.x*2+half; i < NN; i += gridDim.x*2)
    s += bf2f(B[(size_t)i*HH + f]);
  __shared__ float sd[256];
  sd[threadIdx.x]=s; __syncthreads();
  if(half==0) atomicAdd(&hgsum[f], sd[threadIdx.x]+sd[threadIdx.x+128]);
}

// ---------------- tiny decoder, single block ----------------
__global__ __launch_bounds__(256) void kdec(const float* __restrict__ hgsum, const float* __restrict__ eps,
   const float* muW,const float* mub,const float* lvW,const float* lvb,
   const float* decW,const float* decb,
   const float* aW1,const float* ab1,const float* aW2,const float* ab2,
   const float* nW1,const float* nb1,const float* nW2,const float* nb2,
   float* out, float* rowadj, float* rownodes){
  __shared__ float hg[HH], z[LATD], hd[HH], t1[HH], t2[HH];
  int t=threadIdx.x;
  if(t<HH) hg[t]=hgsum[t]*(1.0f/NN);
  __syncthreads();
  if(t<LATD){
    float mu=mub[t], lv=lvb[t];
    for(int k=0;k<HH;k++){ mu += hg[k]*muW[k*LATD+t]; lv += hg[k]*lvW[k*LATD+t]; }
    out[MU_OFF+t]=mu; out[LV_OFF+t]=lv;
    z[t]=mu + eps[t]*expf(0.5f*lv);
  }
  __syncthreads();
  if(t<HH){
    float a=decb[t];
    for(int k=0;k<LATD;k++) a += z[k]*decW[k*HH+t];
    hd[t]=fmaxf(a,0.f);
  }
  __syncthreads();
  if(t<HH){
    float a=ab1[t];
    for(int k=0;k<HH;k++) a += hd[k]*aW1[k*HH+t];
    t1[t]=fmaxf(a,0.f);
  } else {
    int j=t-HH;
    float a=nb1[j];
    for(int k=0;k<HH;k++) a += hd[k]*nW1[k*HH+j];
    t2[j]=fmaxf(a,0.f);
  }
  __syncthreads();
  for(int j=t;j<MAXNN;j+=256){
    float a=ab2[j];
    for(int k=0;k<HH;k++) a += t1[k]*aW2[k*MAXNN+j];
    rowadj[j]=a;
  }
  if(t<HH){
    float a=nb2[t];
    for(int k=0;k<HH;k++) a += t2[k]*nW2[k*HH+t];
    rownodes[t]=a;
  }
}

// ---------------- broadcast the two decoder rows over all N nodes ----------------
__global__ __launch_bounds__(256) void kbcast(const float* __restrict__ rowadj,
                                              const float* __restrict__ rownodes,
                                              float* __restrict__ out){
  __shared__ float row[MAXNN+HH];
  int t=threadIdx.x;
  if(t<MAXNN) row[t]=rowadj[t];
  if(t<HH) row[MAXNN+t]=rownodes[t];
  __syncthreads();
  int stride=gridDim.x*blockDim.x;
  for(int idx=blockIdx.x*blockDim.x+t; idx<OUT_TOT; idx+=stride){
    if(idx<ADJ_TOT) out[idx]=row[idx%MAXNN];
    else { int j=(idx-ADJ_TOT)&(HH-1); out[idx]=row[MAXNN+j]; }
  }
}

extern "C" void kernel_launch(void* const* d_in, const int* in_sizes, int n_in,
                              void* d_out, int out_size, void* d_ws, size_t ws_size,
                              hipStream_t stream){
  const float* x   = (const float*)d_in[0];
  const int*   ei  = (const int*)d_in[1];
  const float* ea  = (const float*)d_in[2];
  const float* eps = (const float*)d_in[3];
  const float* W1  =(const float*)d_in[5];
  const float* as1 =(const float*)d_in[6];
  const float* ad1 =(const float*)d_in[7];
  const float* We1 =(const float*)d_in[8];
  const float* ae1 =(const float*)d_in[9];
  const float* b1  =(const float*)d_in[10];
  const float* W2  =(const float*)d_in[11];
  const float* as2 =(const float*)d_in[12];
  const float* ad2 =(const float*)d_in[13];
  const float* We2 =(const float*)d_in[14];
  const float* ae2 =(const float*)d_in[15];
  const float* b2  =(const float*)d_in[16];
  const float* muW =(const float*)d_in[17];
  const float* mub =(const float*)d_in[18];
  const float* lvW =(const float*)d_in[19];
  const float* lvb =(const float*)d_in[20];
  const float* decW=(const float*)d_in[21];
  const float* decb=(const float*)d_in[22];
  const float* aW1 =(const float*)d_in[23];
  const float* ab1 =(const float*)d_in[24];
  const float* aW2 =(const float*)d_in[25];
  const float* ab2 =(const float*)d_in[26];
  const float* nW1 =(const float*)d_in[27];
  const float* nb1 =(const float*)d_in[28];
  const float* nW2 =(const float*)d_in[29];
  const float* nb2 =(const float*)d_in[30];
  float* out=(float*)d_out;

  char* w=(char*)d_ws;
  unsigned short* Abf = (unsigned short*)w; w += (size_t)NN*HH*2;
  unsigned short* Bbf = (unsigned short*)w; w += (size_t)NN*HH*2;
  unsigned short* Wp1 = (unsigned short*)w; w += (size_t)HH*HH*2;
  unsigned short* Wp2 = (unsigned short*)w; w += (size_t)HH*HH*2;
  float4* csr      = (float4*)w; w += (size_t)EF*16;
  float*  alphabuf = (float*)w;  w += (size_t)EF*4;
  int*    srcbuf   = (int*)w;    w += (size_t)EF*4;
  int*    erank    = (int*)w;    w += (size_t)EE*4;
  int*    rowstart = (int*)w;    w += (size_t)(NN+1)*4;
  int*    ideg     = (int*)w;    w += (size_t)NN*4;
  float*  asrc     = (float*)w;  w += (size_t)NN*4;
  float*  adst     = (float*)w;  w += (size_t)NN*4;
  float*  hgsum    = (float*)w;  w += 128*4;
  float*  wa1      = (float*)w;  w += 16*4;
  float*  wa2      = (float*)w;  w += 16*4;
  float*  rowadj   = (float*)w;  w += 256*4;
  float*  rownodes = (float*)w;  w += 128*4;
  int*    blocksum = (int*)w;    w += 64*4;
  int*    blockoff = (int*)w;    w += 64*4;

  int nb = (NN+1023)/1024; // 49
  int gemmblocks = (NN+63)/64;   // 782
  int gatblocks  = (NN+3)/4;     // 12500

  hipLaunchKernelGGL(kinit, dim3((NN+255)/256), dim3(256), 0, stream, ideg, hgsum);
  hipLaunchKernelGGL(kwa, dim3(1), dim3(64), 0, stream, We1, ae1, We2, ae2, wa1, wa2);
  hipLaunchKernelGGL(kwprep, dim3((HH*HH+255)/256), dim3(256), 0, stream, W1, W2, Wp1, Wp2);
  hipLaunchKernelGGL(kdeg, dim3((EE+255)/256), dim3(256), 0, stream, ei, ideg, erank);
  hipLaunchKernelGGL(kscan1, dim3(nb), dim3(1024), 0, stream, ideg, rowstart, blocksum);
  hipLaunchKernelGGL(kscan2, dim3(1), dim3(64), 0, stream, blocksum, blockoff, nb);
  hipLaunchKernelGGL(kscan3, dim3((NN+255)/256), dim3(256), 0, stream, rowstart, blockoff, nb);
  hipLaunchKernelGGL(kscatter, dim3((EE+255)/256), dim3(256), 0, stream,
                     ei, ea, wa1, wa2, rowstart, erank, csr);
  hipLaunchKernelGGL(kself, dim3((NN+15)/16), dim3(256), 0, stream, rowstart, ideg, csr);
  // layer 1 (fp32 x input)
  hipLaunchKernelGGL(kgemm3, dim3(gemmblocks), dim3(256), 0, stream,
                     (const void*)x, 1, Wp1, as1, ad1, Abf, asrc, adst);
  hipLaunchKernelGGL(kgat,  dim3(gatblocks), dim3(256), 0, stream, Abf, asrc, adst, rowstart, csr, 0, b1, alphabuf, srcbuf, Bbf);
  // layer 2 (bf16 input)
  hipLaunchKernelGGL(kgemm3, dim3(gemmblocks), dim3(256), 0, stream,
                     (const void*)Bbf, 0, Wp2, as2, ad2, Abf, asrc, adst);
  hipLaunchKernelGGL(kgat,  dim3(gatblocks), dim3(256), 0, stream, Abf, asrc, adst, rowstart, csr, 1, b2, alphabuf, srcbuf, Bbf);
  // graph embedding + decoder + broadcast
  hipLaunchKernelGGL(khg,   dim3(512), dim3(256), 0, stream, Bbf, hgsum);
  hipLaunchKernelGGL(kdec,  dim3(1), dim3(256), 0, stream, hgsum, eps,
                     muW,mub,lvW,lvb,decW,decb,aW1,ab1,aW2,ab2,nW1,nb1,nW2,nb2,
                     out, rowadj, rownodes);
  hipLaunchKernelGGL(kbcast, dim3(2048), dim3(256), 0, stream, rowadj, rownodes, out);
}

// Round 11
// 445.482 us; speedup vs baseline: 1.0901x; 1.0165x over previous
//
#include <hip/hip_runtime.h>
#include <math.h>

#define NN   50000
#define EE   800000
#define EF   850000   // EE + NN self loops
#define HH   128
#define FE   16
#define LATD 64
#define MAXNN 200

#define ADJ_TOT   10000000   // NN*MAXNN
#define NODES_TOT 6400000    // NN*HH
#define OUT_TOT   16400000   // ADJ_TOT + NODES_TOT
#define MU_OFF    16400000
#define LV_OFF    16400064

typedef __attribute__((ext_vector_type(8))) short bf16x8;
typedef __attribute__((ext_vector_type(4))) float f32x4;
typedef __attribute__((ext_vector_type(2))) float f32x2;

__device__ __forceinline__ unsigned short f2bf(float f){
  unsigned int u = __float_as_uint(f);
  unsigned int r = (u + 0x7FFFu + ((u>>16)&1u)) >> 16;   // RNE
  return (unsigned short)r;
}
__device__ __forceinline__ float bf2f(unsigned short h){
  return __uint_as_float(((unsigned int)h)<<16);
}

// ---------------- merged setup: init + wa fold + W transpose/pack ----------------
__global__ void ksetup(int* ideg, float* hgsum,
                       const float* We1, const float* ae1, const float* We2, const float* ae2,
                       float* wa1, float* wa2,
                       const float* W1, const float* W2,
                       unsigned short* Wp1, unsigned short* Wp2){
  int i = blockIdx.x*blockDim.x + threadIdx.x;
  if(i < NN) ideg[i]=0;
  if(i < HH) hgsum[i]=0.f;
  if(i < FE){
    float s1=0.f, s2=0.f;
    for(int j=0;j<HH;j++){ s1 += We1[i*HH+j]*ae1[j]; s2 += We2[i*HH+j]*ae2[j]; }
    wa1[i]=s1; wa2[i]=s2;
  }
  if(i < HH*HH){
    int n = i >> 7, k = i & 127;
    Wp1[i] = f2bf(W1[k*HH + n]);
    Wp2[i] = f2bf(W2[k*HH + n]);
  }
}

// degree count + within-row rank (atomic return)
__global__ void kdeg(const int* __restrict__ ei, int* ideg, unsigned short* __restrict__ erank){
  int e = blockIdx.x*blockDim.x + threadIdx.x;
  if(e<EE) erank[e] = (unsigned short)atomicAdd(&ideg[ei[EE+e]], 1);
}

// ---------------- exclusive scan of rowlen = ideg+1 ----------------
__global__ void kscan1(const int* __restrict__ ideg, int* rowstart, int* blocksum){
  __shared__ int sd[1024];
  int t=threadIdx.x; int i=blockIdx.x*1024+t;
  int v = (i<NN)? (ideg[i]+1) : 0;
  sd[t]=v; __syncthreads();
  for(int off=1; off<1024; off<<=1){
    int x = (t>=off)? sd[t-off] : 0;
    __syncthreads();
    sd[t] += x;
    __syncthreads();
  }
  if(i<NN) rowstart[i] = sd[t]-v;
  if(t==1023) blocksum[blockIdx.x]=sd[1023];
}
__global__ void kscan2(const int* blocksum, int* blockoff, int nb){
  if(threadIdx.x==0){
    int run=0;
    for(int b=0;b<nb;b++){ blockoff[b]=run; run+=blocksum[b]; }
    blockoff[nb]=run;
  }
}
__global__ void kscan3(int* rowstart, const int* __restrict__ blockoff, int nb){
  int i=blockIdx.x*blockDim.x+threadIdx.x;
  if(i<NN) rowstart[i]+=blockoff[i>>10];
  if(i==0) rowstart[NN]=blockoff[nb];
}

// ---------------- CSR scatter: one packed 8B entry per edge, NO atomic ----------------
// entry = {src, bf16(et1) | bf16(et2)<<16}
__global__ void kscatter(const int* __restrict__ ei, const float* __restrict__ ea,
                         const float* __restrict__ wa1, const float* __restrict__ wa2,
                         const int* __restrict__ rowstart, const unsigned short* __restrict__ erank,
                         uint2* __restrict__ csr){
  int e=blockIdx.x*blockDim.x+threadIdx.x;
  if(e>=EE) return;
  int s=ei[e], d=ei[EE+e];
  const float4* ea4 = (const float4*)(ea + (size_t)e*FE);
  float4 v0=ea4[0], v1=ea4[1], v2=ea4[2], v3=ea4[3];
  float va[16]={v0.x,v0.y,v0.z,v0.w, v1.x,v1.y,v1.z,v1.w,
                v2.x,v2.y,v2.z,v2.w, v3.x,v3.y,v3.z,v3.w};
  float d1=0.f,d2=0.f;
  #pragma unroll
  for(int f=0;f<FE;f++){ d1+=va[f]*wa1[f]; d2+=va[f]*wa2[f]; }
  int pos = rowstart[d] + (int)erank[e];
  uint2 en; en.x = (unsigned)s;
  en.y = (unsigned)f2bf(d1) | ((unsigned)f2bf(d2)<<16);
  csr[pos] = en;
}

// self-loop entry: et = mean of row's et values (16-lane group per node)
__global__ __launch_bounds__(256) void kself(const int* __restrict__ rowstart,
                      const int* __restrict__ ideg,
                      uint2* __restrict__ csr){
  int tid = threadIdx.x;
  int l16 = tid & 15;
  int grp = tid >> 4;
  int i = blockIdx.x*16 + grp;
  if(i>=NN) return;
  int base = rowstart[i]; int deg = ideg[i];
  float s1=0.f, s2=0.f;
  for(int k=l16;k<deg;k+=16){
    uint2 en=csr[base+k];
    s1 += bf2f((unsigned short)(en.y & 0xFFFFu));
    s2 += bf2f((unsigned short)(en.y >> 16));
  }
  #pragma unroll
  for(int m=8;m>=1;m>>=1){ s1+=__shfl_xor(s1,m,16); s2+=__shfl_xor(s2,m,16); }
  if(l16==0){
    float dg = (float)deg; if(dg<1.f) dg=1.f;
    uint2 en; en.x=(unsigned)i;
    en.y = (unsigned)f2bf(s1/dg) | ((unsigned)f2bf(s2/dg)<<16);
    csr[base+deg] = en;
  }
}

// ---------------- MFMA GEMM: A8 = fp8( h @ W ), fused asrc/adst ----------------
__global__ __launch_bounds__(256) void kgemm3(const void* __restrict__ hin, int h_is_fp32,
    const unsigned short* __restrict__ Wp,
    const float* __restrict__ atts, const float* __restrict__ attd,
    unsigned char* __restrict__ A8, float* __restrict__ asrc, float* __restrict__ adst){
  int lane = threadIdx.x & 63;
  int wid  = threadIdx.x >> 6;
  int l = lane & 15, q = lane >> 4;
  int r0 = blockIdx.x*64 + wid*16;
  if(r0 >= NN) return;
  const unsigned short* hb = (const unsigned short*)hin;
  const float*          hf = (const float*)hin;
  int row = r0 + l;

  f32x4 acc[8];
  #pragma unroll
  for(int t=0;t<8;t++) acc[t]=(f32x4){0.f,0.f,0.f,0.f};

  #pragma unroll
  for(int kb=0;kb<4;kb++){
    bf16x8 a;
    if(h_is_fp32){
      const float* p = hf + (size_t)row*HH + kb*32 + q*8;
      float4 u0 = *(const float4*)(p);
      float4 u1 = *(const float4*)(p+4);
      a[0]=(short)f2bf(u0.x); a[1]=(short)f2bf(u0.y); a[2]=(short)f2bf(u0.z); a[3]=(short)f2bf(u0.w);
      a[4]=(short)f2bf(u1.x); a[5]=(short)f2bf(u1.y); a[6]=(short)f2bf(u1.z); a[7]=(short)f2bf(u1.w);
    } else {
      a = *(const bf16x8*)(hb + (size_t)row*HH + kb*32 + q*8);
    }
    #pragma unroll
    for(int t=0;t<8;t++){
      bf16x8 b = *(const bf16x8*)(Wp + (size_t)(t*16+l)*HH + kb*32 + q*8);
      acc[t] = __builtin_amdgcn_mfma_f32_16x16x32_bf16(a, b, acc[t], 0,0,0);
    }
  }

  // fused row-dots: reduce over l (16 lanes)
  float av[8], dv[8];
  #pragma unroll
  for(int t=0;t<8;t++){ av[t]=atts[t*16+l]; dv[t]=attd[t*16+l]; }
  #pragma unroll
  for(int reg=0;reg<4;reg++){
    float ps=0.f, pd=0.f;
    #pragma unroll
    for(int t=0;t<8;t++){ ps+=acc[t][reg]*av[t]; pd+=acc[t][reg]*dv[t]; }
    #pragma unroll
    for(int m=8;m>=1;m>>=1){ ps+=__shfl_xor(ps,m,16); pd+=__shfl_xor(pd,m,16); }
    if(l==0){ int R=r0+q*4+reg; asrc[R]=ps; adst[R]=pd; }
  }
  // store G as fp8 e4m3 (byte stores; wave covers whole 128B rows -> L2 merges)
  #pragma unroll
  for(int t=0;t<8;t++)
    #pragma unroll
    for(int reg=0;reg<4;reg++){
      int pk = __builtin_amdgcn_cvt_pk_fp8_f32(acc[t][reg], 0.f, 0, false);
      A8[(size_t)(r0+q*4+reg)*HH + t*16 + l] = (unsigned char)(pk & 0xFF);
    }
}

// ---------------- GAT softmax-aggregate: ONE WAVE per dst node, fp8 gather ----------
// lane (lq=lane>>3, lf=lane&7) loads uint4 = 16 fp8 feats of edge c*8+lq's row
// -> one dwordx4 covers 8 edges; shfl_xor(8/16/32) folds the 8 edge-subsets.
__global__ __launch_bounds__(256) void kgat(const unsigned char* __restrict__ A8,
    const float* __restrict__ asrc, const float* __restrict__ adst,
    const int* __restrict__ rowstart, const uint2* __restrict__ csr,
    int etsel, const float* __restrict__ bias,
    float* __restrict__ alphabuf, int* __restrict__ srcbuf,
    unsigned short* __restrict__ Bout){
  int lane = threadIdx.x & 63;
  int wid  = threadIdx.x >> 6;
  int i = blockIdx.x*4 + wid;
  if(i >= NN) return;
  int base = rowstart[i]; int len = rowstart[i+1]-base;
  int lq = lane >> 3;              // edge slot within chunk (0..7)
  int lf = lane & 7;               // feature 16B-chunk (feats lf*16 .. lf*16+15)
  float adi = adst[i];
  float den;
  float av[16];
  #pragma unroll
  for(int j=0;j<16;j++) av[j]=0.f;

  if(__builtin_expect(len <= 64, 1)){
    // phase 1: one edge per lane
    float a = -1e30f; int s=0;
    if(lane < len){
      uint2 en = csr[base+lane];
      s = (int)en.x;
      float et = etsel ? bf2f((unsigned short)(en.y>>16)) : bf2f((unsigned short)(en.y&0xFFFFu));
      a = asrc[s] + adi + et;
      a = a>0.f ? a : 0.2f*a;            // leaky_relu 0.2
    }
    float m = a;
    #pragma unroll
    for(int mk=32;mk>=1;mk>>=1) m = fmaxf(m, __shfl_xor(m, mk));
    float ex = (lane<len) ? __expf(a-m) : 0.f;
    float sm = ex;
    #pragma unroll
    for(int mk=32;mk>=1;mk>>=1) sm += __shfl_xor(sm, mk);
    den = sm;
    // phase 3: 8-edge chunks, 2-deep pipeline (idx <= 63 always since len<=64)
    int chunks = (len+7)>>3;
    float wk = __shfl(ex, lq);
    int   sk = __shfl(s, lq);
    uint4 p  = *((const uint4*)(A8 + (size_t)sk*HH) + lf);
    for(int c=0;c<chunks;c++){
      float wc = wk; uint4 pc = p;
      if(c+1<chunks){
        int idx = (c+1)*8 + lq;
        wk = __shfl(ex, idx);
        sk = __shfl(s, idx);
        p  = *((const uint4*)(A8 + (size_t)sk*HH) + lf);
      }
      f32x2 v;
      v=__builtin_amdgcn_cvt_pk_f32_fp8(pc.x,false); av[0]+=wc*v[0];  av[1]+=wc*v[1];
      v=__builtin_amdgcn_cvt_pk_f32_fp8(pc.x,true ); av[2]+=wc*v[0];  av[3]+=wc*v[1];
      v=__builtin_amdgcn_cvt_pk_f32_fp8(pc.y,false); av[4]+=wc*v[0];  av[5]+=wc*v[1];
      v=__builtin_amdgcn_cvt_pk_f32_fp8(pc.y,true ); av[6]+=wc*v[0];  av[7]+=wc*v[1];
      v=__builtin_amdgcn_cvt_pk_f32_fp8(pc.z,false); av[8]+=wc*v[0];  av[9]+=wc*v[1];
      v=__builtin_amdgcn_cvt_pk_f32_fp8(pc.z,true ); av[10]+=wc*v[0]; av[11]+=wc*v[1];
      v=__builtin_amdgcn_cvt_pk_f32_fp8(pc.w,false); av[12]+=wc*v[0]; av[13]+=wc*v[1];
      v=__builtin_amdgcn_cvt_pk_f32_fp8(pc.w,true ); av[14]+=wc*v[0]; av[15]+=wc*v[1];
    }
  } else {
    // rare fallback: strided two-pass with global spill, same chunked gather
    float lm = -1e30f;
    for(int k=lane;k<len;k+=64){
      uint2 en = csr[base+k];
      int s = (int)en.x;
      float et = etsel ? bf2f((unsigned short)(en.y>>16)) : bf2f((unsigned short)(en.y&0xFFFFu));
      float a = asrc[s] + adi + et;
      a = a>0.f ? a : 0.2f*a;
      alphabuf[base+k]=a; srcbuf[base+k]=s;
      lm = fmaxf(lm,a);
    }
    #pragma unroll
    for(int mk=32;mk>=1;mk>>=1) lm = fmaxf(lm, __shfl_xor(lm, mk));
    float ls=0.f;
    for(int k=lane;k<len;k+=64){
      float ex = __expf(alphabuf[base+k]-lm);
      alphabuf[base+k]=ex; ls+=ex;
    }
    #pragma unroll
    for(int mk=32;mk>=1;mk>>=1) ls += __shfl_xor(ls, mk);
    den = ls;
    int chunks = (len+7)>>3;
    for(int c=0;c<chunks;c++){
      int idx = c*8 + lq;
      float wc = (idx<len)? alphabuf[base+idx] : 0.f;
      int   sk = (idx<len)? srcbuf[base+idx] : 0;
      uint4 pc = *((const uint4*)(A8 + (size_t)sk*HH) + lf);
      f32x2 v;
      v=__builtin_amdgcn_cvt_pk_f32_fp8(pc.x,false); av[0]+=wc*v[0];  av[1]+=wc*v[1];
      v=__builtin_amdgcn_cvt_pk_f32_fp8(pc.x,true ); av[2]+=wc*v[0];  av[3]+=wc*v[1];
      v=__builtin_amdgcn_cvt_pk_f32_fp8(pc.y,false); av[4]+=wc*v[0];  av[5]+=wc*v[1];
      v=__builtin_amdgcn_cvt_pk_f32_fp8(pc.y,true ); av[6]+=wc*v[0];  av[7]+=wc*v[1];
      v=__builtin_amdgcn_cvt_pk_f32_fp8(pc.z,false); av[8]+=wc*v[0];  av[9]+=wc*v[1];
      v=__builtin_amdgcn_cvt_pk_f32_fp8(pc.z,true ); av[10]+=wc*v[0]; av[11]+=wc*v[1];
      v=__builtin_amdgcn_cvt_pk_f32_fp8(pc.w,false); av[12]+=wc*v[0]; av[13]+=wc*v[1];
      v=__builtin_amdgcn_cvt_pk_f32_fp8(pc.w,true ); av[14]+=wc*v[0]; av[15]+=wc*v[1];
    }
  }
  // fold the 8 edge-subsets (lanes with same lf hold same features)
  #pragma unroll
  for(int j=0;j<16;j++){
    av[j] += __shfl_xor(av[j],8);
    av[j] += __shfl_xor(av[j],16);
    av[j] += __shfl_xor(av[j],32);
  }
  if(lq==0){
    float inv = 1.f/den;
    const float4* bp = (const float4*)(bias + lf*16);
    float4 b0=bp[0], b1=bp[1], b2=bp[2], b3=bp[3];
    float o[16];
    o[0] =fmaxf(av[0] *inv+b0.x,0.f); o[1] =fmaxf(av[1] *inv+b0.y,0.f);
    o[2] =fmaxf(av[2] *inv+b0.z,0.f); o[3] =fmaxf(av[3] *inv+b0.w,0.f);
    o[4] =fmaxf(av[4] *inv+b1.x,0.f); o[5] =fmaxf(av[5] *inv+b1.y,0.f);
    o[6] =fmaxf(av[6] *inv+b1.z,0.f); o[7] =fmaxf(av[7] *inv+b1.w,0.f);
    o[8] =fmaxf(av[8] *inv+b2.x,0.f); o[9] =fmaxf(av[9] *inv+b2.y,0.f);
    o[10]=fmaxf(av[10]*inv+b2.z,0.f); o[11]=fmaxf(av[11]*inv+b2.w,0.f);
    o[12]=fmaxf(av[12]*inv+b3.x,0.f); o[13]=fmaxf(av[13]*inv+b3.y,0.f);
    o[14]=fmaxf(av[14]*inv+b3.z,0.f); o[15]=fmaxf(av[15]*inv+b3.w,0.f);
    uint4 ov1, ov2;
    ov1.x=(unsigned)f2bf(o[0]) |((unsigned)f2bf(o[1]) <<16);
    ov1.y=(unsigned)f2bf(o[2]) |((unsigned)f2bf(o[3]) <<16);
    ov1.z=(unsigned)f2bf(o[4]) |((unsigned)f2bf(o[5]) <<16);
    ov1.w=(unsigned)f2bf(o[6]) |((unsigned)f2bf(o[7]) <<16);
    ov2.x=(unsigned)f2bf(o[8]) |((unsigned)f2bf(o[9]) <<16);
    ov2.y=(unsigned)f2bf(o[10])|((unsigned)f2bf(o[11])<<16);
    ov2.z=(unsigned)f2bf(o[12])|((unsigned)f2bf(o[13])<<16);
    ov2.w=(unsigned)f2bf(o[14])|((unsigned)f2bf(o[15])<<16);
    uint4* outp = (uint4*)(Bout + (size_t)i*HH + lf*16);
    outp[0]=ov1; outp[1]=ov2;
  }
}

// ---------------- column mean (bf16 input): grid-strided, 512 blocks ----------------
__global__ __launch_bounds__(256) void khg(const unsigned short* __restrict__ B, float* hgsum){
  int f = threadIdx.x & 127;      // column
  int half = threadIdx.x >> 7;    // 0/1
  float s=0.f;
  for(int i = blockIdx.x*2+half; i < NN; i += gridDim.x*2)
    s += bf2f(B[(size_t)i*HH + f]);
  __shared__ float sd[256];
  sd[threadIdx.x]=s; __syncthreads();
  if(half==0) atomicAdd(&hgsum[f], sd[threadIdx.x]+sd[threadIdx.x+128]);
}

// ---------------- tiny decoder, single block ----------------
__global__ __launch_bounds__(256) void kdec(const float* __restrict__ hgsum, const float* __restrict__ eps,
   const float* muW,const float* mub,const float* lvW,const float* lvb,
   const float* decW,const float* decb,
   const float* aW1,const float* ab1,const float* aW2,const float* ab2,
   const float* nW1,const float* nb1,const float* nW2,const float* nb2,
   float* out, float* rowadj, float* rownodes){
  __shared__ float hg[HH], z[LATD], hd[HH], t1[HH], t2[HH];
  int t=threadIdx.x;
  if(t<HH) hg[t]=hgsum[t]*(1.0f/NN);
  __syncthreads();
  if(t<LATD){
    float mu=mub[t], lv=lvb[t];
    for(int k=0;k<HH;k++){ mu += hg[k]*muW[k*LATD+t]; lv += hg[k]*lvW[k*LATD+t]; }
    out[MU_OFF+t]=mu; out[LV_OFF+t]=lv;
    z[t]=mu + eps[t]*expf(0.5f*lv);
  }
  __syncthreads();
  if(t<HH){
    float a=decb[t];
    for(int k=0;k<LATD;k++) a += z[k]*decW[k*HH+t];
    hd[t]=fmaxf(a,0.f);
  }
  __syncthreads();
  if(t<HH){
    float a=ab1[t];
    for(int k=0;k<HH;k++) a += hd[k]*aW1[k*HH+t];
    t1[t]=fmaxf(a,0.f);
  } else {
    int j=t-HH;
    float a=nb1[j];
    for(int k=0;k<HH;k++) a += hd[k]*nW1[k*HH+j];
    t2[j]=fmaxf(a,0.f);
  }
  __syncthreads();
  for(int j=t;j<MAXNN;j+=256){
    float a=ab2[j];
    for(int k=0;k<HH;k++) a += t1[k]*aW2[k*MAXNN+j];
    rowadj[j]=a;
  }
  if(t<HH){
    float a=nb2[t];
    for(int k=0;k<HH;k++) a += t2[k]*nW2[k*HH+t];
    rownodes[t]=a;
  }
}

// ---------------- broadcast the two decoder rows over all N nodes ----------------
__global__ __launch_bounds__(256) void kbcast(const float* __restrict__ rowadj,
                                              const float* __restrict__ rownodes,
                                              float* __restrict__ out){
  __shared__ float row[MAXNN+HH];
  int t=threadIdx.x;
  if(t<MAXNN) row[t]=rowadj[t];
  if(t<HH) row[MAXNN+t]=rownodes[t];
  __syncthreads();
  int stride=gridDim.x*blockDim.x;
  for(int idx=blockIdx.x*blockDim.x+t; idx<OUT_TOT; idx+=stride){
    if(idx<ADJ_TOT) out[idx]=row[idx%MAXNN];
    else { int j=(idx-ADJ_TOT)&(HH-1); out[idx]=row[MAXNN+j]; }
  }
}

extern "C" void kernel_launch(void* const* d_in, const int* in_sizes, int n_in,
                              void* d_out, int out_size, void* d_ws, size_t ws_size,
                              hipStream_t stream){
  const float* x   = (const float*)d_in[0];
  const int*   ei  = (const int*)d_in[1];
  const float* ea  = (const float*)d_in[2];
  const float* eps = (const float*)d_in[3];
  const float* W1  =(const float*)d_in[5];
  const float* as1 =(const float*)d_in[6];
  const float* ad1 =(const float*)d_in[7];
  const float* We1 =(const float*)d_in[8];
  const float* ae1 =(const float*)d_in[9];
  const float* b1  =(const float*)d_in[10];
  const float* W2  =(const float*)d_in[11];
  const float* as2 =(const float*)d_in[12];
  const float* ad2 =(const float*)d_in[13];
  const float* We2 =(const float*)d_in[14];
  const float* ae2 =(const float*)d_in[15];
  const float* b2  =(const float*)d_in[16];
  const float* muW =(const float*)d_in[17];
  const float* mub =(const float*)d_in[18];
  const float* lvW =(const float*)d_in[19];
  const float* lvb =(const float*)d_in[20];
  const float* decW=(const float*)d_in[21];
  const float* decb=(const float*)d_in[22];
  const float* aW1 =(const float*)d_in[23];
  const float* ab1 =(const float*)d_in[24];
  const float* aW2 =(const float*)d_in[25];
  const float* ab2 =(const float*)d_in[26];
  const float* nW1 =(const float*)d_in[27];
  const float* nb1 =(const float*)d_in[28];
  const float* nW2 =(const float*)d_in[29];
  const float* nb2 =(const float*)d_in[30];
  float* out=(float*)d_out;

  char* w=(char*)d_ws;
  unsigned char*  A8  = (unsigned char*)w;  w += (size_t)NN*HH;      // 6.4 MB fp8
  unsigned short* Bbf = (unsigned short*)w; w += (size_t)NN*HH*2;    // 12.8 MB bf16
  unsigned short* Wp1 = (unsigned short*)w; w += (size_t)HH*HH*2;
  unsigned short* Wp2 = (unsigned short*)w; w += (size_t)HH*HH*2;
  uint2*  csr      = (uint2*)w;  w += (size_t)EF*8;                  // 6.8 MB
  float*  alphabuf = (float*)w;  w += (size_t)EF*4;
  int*    srcbuf   = (int*)w;    w += (size_t)EF*4;
  unsigned short* erank = (unsigned short*)w; w += (size_t)EE*2;
  int*    rowstart = (int*)w;    w += (size_t)(NN+1)*4;
  int*    ideg     = (int*)w;    w += (size_t)NN*4;
  float*  asrc     = (float*)w;  w += (size_t)NN*4;
  float*  adst     = (float*)w;  w += (size_t)NN*4;
  float*  hgsum    = (float*)w;  w += 128*4;
  float*  wa1      = (float*)w;  w += 16*4;
  float*  wa2      = (float*)w;  w += 16*4;
  float*  rowadj   = (float*)w;  w += 256*4;
  float*  rownodes = (float*)w;  w += 128*4;
  int*    blocksum = (int*)w;    w += 64*4;
  int*    blockoff = (int*)w;    w += 64*4;

  int nb = (NN+1023)/1024; // 49
  int gemmblocks = (NN+63)/64;   // 782
  int gatblocks  = (NN+3)/4;     // 12500

  hipLaunchKernelGGL(ksetup, dim3((NN+255)/256), dim3(256), 0, stream,
                     ideg, hgsum, We1, ae1, We2, ae2, wa1, wa2, W1, W2, Wp1, Wp2);
  hipLaunchKernelGGL(kdeg, dim3((EE+255)/256), dim3(256), 0, stream, ei, ideg, erank);
  hipLaunchKernelGGL(kscan1, dim3(nb), dim3(1024), 0, stream, ideg, rowstart, blocksum);
  hipLaunchKernelGGL(kscan2, dim3(1), dim3(64), 0, stream, blocksum, blockoff, nb);
  hipLaunchKernelGGL(kscan3, dim3((NN+255)/256), dim3(256), 0, stream, rowstart, blockoff, nb);
  hipLaunchKernelGGL(kscatter, dim3((EE+255)/256), dim3(256), 0, stream,
                     ei, ea, wa1, wa2, rowstart, erank, csr);
  hipLaunchKernelGGL(kself, dim3((NN+15)/16), dim3(256), 0, stream, rowstart, ideg, csr);
  // layer 1 (fp32 x input)
  hipLaunchKernelGGL(kgemm3, dim3(gemmblocks), dim3(256), 0, stream,
                     (const void*)x, 1, Wp1, as1, ad1, A8, asrc, adst);
  hipLaunchKernelGGL(kgat,  dim3(gatblocks), dim3(256), 0, stream, A8, asrc, adst, rowstart, csr, 0, b1, alphabuf, srcbuf, Bbf);
  // layer 2 (bf16 input)
  hipLaunchKernelGGL(kgemm3, dim3(gemmblocks), dim3(256), 0, stream,
                     (const void*)Bbf, 0, Wp2, as2, ad2, A8, asrc, adst);
  hipLaunchKernelGGL(kgat,  dim3(gatblocks), dim3(256), 0, stream, A8, asrc, adst, rowstart, csr, 1, b2, alphabuf, srcbuf, Bbf);
  // graph embedding + decoder + broadcast
  hipLaunchKernelGGL(khg,   dim3(512), dim3(256), 0, stream, Bbf, hgsum);
  hipLaunchKernelGGL(kdec,  dim3(1), dim3(256), 0, stream, hgsum, eps,
                     muW,mub,lvW,lvb,decW,decb,aW1,ab1,aW2,ab2,nW1,nb1,nW2,nb2,
                     out, rowadj, rownodes);
  hipLaunchKernelGGL(kbcast, dim3(2048), dim3(256), 0, stream, rowadj, rownodes, out);
}